// Round 6
// baseline (373.981 us; speedup 1.0000x reference)
//
#include <hip/hip_runtime.h>
#include <hip/hip_bf16.h>

#define DIM 512
#define BB 8
#define LL 8192
#define ML (BB * LL)  // 65536 rows

typedef __attribute__((ext_vector_type(4))) float f32x4;
typedef __attribute__((ext_vector_type(8))) short short8;

__device__ __forceinline__ void gl_lds16(const __hip_bfloat16* g, __hip_bfloat16* l) {
  __builtin_amdgcn_global_load_lds(
      (const __attribute__((address_space(1))) void*)g,
      (__attribute__((address_space(3))) void*)l, 16, 0, 0);
}

__device__ __forceinline__ unsigned short bf16_bits(float f) {
  __hip_bfloat16 h = __float2bfloat16(f);
  return *reinterpret_cast<unsigned short*>(&h);
}

// ---------------- zero the row-sumsq accumulator (deterministic, no memset) -
__global__ void zero_ss(float* __restrict__ ss) {
  ss[blockIdx.x * 256 + threadIdx.x] = 0.0f;
}

// ---------------- depthwise causal conv (K=4, left pad 3) + cast to bf16 ----
__global__ void conv_cast_kernel(const float* __restrict__ x,
                                 const float* __restrict__ cwt,
                                 const float* __restrict__ cb,
                                 __hip_bfloat16* __restrict__ xc) {
  const int tid = blockIdx.x * 256 + threadIdx.x;
  const int d = (tid & 127) << 2;  // 0..508 step 4
  const int bl = tid >> 7;
  const int l = bl & (LL - 1);
  float4 acc = *(const float4*)(cb + d);
  float4 w[4];
#pragma unroll
  for (int k = 0; k < 4; ++k) w[k] = *(const float4*)(cwt + k * DIM + d);
#pragma unroll
  for (int k = 0; k < 4; ++k) {
    if (l - 3 + k >= 0) {
      const float4 xv = *(const float4*)(x + (size_t)(bl - 3 + k) * DIM + d);
      acc.x += xv.x * w[k].x;
      acc.y += xv.y * w[k].y;
      acc.z += xv.z * w[k].z;
      acc.w += xv.w * w[k].w;
    }
  }
  ushort4 o;
  o.x = bf16_bits(acc.x);
  o.y = bf16_bits(acc.y);
  o.z = bf16_bits(acc.z);
  o.w = bf16_bits(acc.w);
  *(ushort4*)((unsigned short*)xc + (size_t)bl * DIM + d) = o;
}

// ---------------- weight prep: cast (or transpose-cast) one 512x512 weight --
__global__ void prep_w(const float* __restrict__ src,
                       __hip_bfloat16* __restrict__ dst, int transpose,
                       const float* __restrict__ cw, float* __restrict__ cwt) {
  const int i = blockIdx.x * 256 + threadIdx.x;  // 0..262143
  if (transpose)
    dst[(size_t)(i & 511) * DIM + (i >> 9)] = __float2bfloat16(src[i]);
  else
    dst[i] = __float2bfloat16(src[i]);
  if (cwt != nullptr && i < DIM * 4) cwt[(i & 3) * DIM + (i >> 2)] = cw[i];
}

// ---------------- GEMM: C[M,N] = A[M,K](bf16) @ Bt[N,K](bf16)^T, f32 acc ----
// 256x256 tile, BK=32, 8 waves (2Mx4N), per-wave 128x64 (acc[8][4]).
// 4-deep K-tile LDS ring, one raw s_barrier + counted vmcnt per K-tile
// (never 0 until the tail). T2 chunk-swizzle, T1 XCD swizzle, T5 setprio.
// EPI 0: write C1 bf16 + per-row sum-of-squares atomics into ss
// EPI 1: v *= 1/max(sqrt(ss[r]),eps); exact GELU -> bf16
// EPI 2: out f32 = v + (1/max(sqrt(ss[r]),eps)) * C1_bf16[off]  (residual q)
template <int EPI>
__global__ __launch_bounds__(512, 2) void gemm_bt(
    const __hip_bfloat16* __restrict__ A, const __hip_bfloat16* __restrict__ Bt,
    float* __restrict__ Cf, __hip_bfloat16* __restrict__ Cb,
    const __hip_bfloat16* __restrict__ C1, float* __restrict__ ss, int M,
    int N, int K) {
  __shared__ __hip_bfloat16 sA[4][256 * 32];
  __shared__ __hip_bfloat16 sB[4][256 * 32];
  // T1: XCD-chunked swizzle (gridDim %8 == 0 here: 512)
  const int nbn = N >> 8;  // 2
  const int bid = blockIdx.x;
  const int swz = (bid & 7) * (gridDim.x >> 3) + (bid >> 3);
  const int bm = swz / nbn;
  const int bn = swz - bm * nbn;
  const int tid = threadIdx.x;
  const int wv = tid >> 6, ln = tid & 63;
  const int wr = wv >> 2, wc = wv & 3;  // wave grid 2M x 4N
  const int idx = ln & 15, kg = ln >> 4;
  const size_t rowA = (size_t)bm * 256, rowB = (size_t)bn * 256;

  f32x4 acc[8][4] = {};

  // staging: slot s = i*512 + tid (i=0,1) covers LDS elems [s*8, s*8+8)
  // row = s>>2 = i*128 + (tid>>2), chunk kc = tid&3.
  // T2: LDS slot (row,kc) holds global chunk kc ^ ((row>>1)&3) = kc^((tid>>3)&3)
  const int rA = wv * 16 + (ln >> 2);
  const int kcl = (((ln & 3) ^ ((ln >> 3) & 3)) << 3);  // elements
  // read side: global chunk kg of row lives in LDS chunk kg ^ ((idx>>1)&3)
  const int kgx = ((kg ^ ((idx >> 1) & 3)) << 3);  // elements

  const __hip_bfloat16* gA0 = A + (rowA + rA) * K + kcl;
  const __hip_bfloat16* gA1 = A + (rowA + 128 + rA) * K + kcl;
  const __hip_bfloat16* gB0 = Bt + (rowB + rA) * K + kcl;
  const __hip_bfloat16* gB1 = Bt + (rowB + 128 + rA) * K + kcl;
  const int lo0 = wv * 512, lo1 = 4096 + wv * 512;  // wave-uniform LDS bases

  const int nt = K >> 5;  // 16 K-tiles

#define STAGE(t, b)                     \
  do {                                  \
    const int k0_ = (t) << 5;           \
    gl_lds16(gA0 + k0_, &sA[(b)][lo0]); \
    gl_lds16(gA1 + k0_, &sA[(b)][lo1]); \
    gl_lds16(gB0 + k0_, &sB[(b)][lo0]); \
    gl_lds16(gB1 + k0_, &sB[(b)][lo1]); \
  } while (0)

  // prologue: fill ring slots 0..2 (12 vm instructions outstanding)
  STAGE(0, 0);
  STAGE(1, 1);
  STAGE(2, 2);

  for (int t = 0; t < nt; ++t) {
    // gate: my stages of tiles t+1, t+2 may remain in flight (4 instrs each)
    if (t < nt - 2)
      asm volatile("s_waitcnt vmcnt(8)" ::: "memory");
    else if (t == nt - 2)
      asm volatile("s_waitcnt vmcnt(4)" ::: "memory");
    else
      asm volatile("s_waitcnt vmcnt(0)" ::: "memory");
    // all waves: tile t landed everywhere; iter t-1 LDS reads all retired
    asm volatile("s_barrier" ::: "memory");
    if (t + 3 < nt) STAGE(t + 3, (t + 3) & 3);

    const __hip_bfloat16* bufA = sA[t & 3];
    const __hip_bfloat16* bufB = sB[t & 3];
    short8 af[8], bfv[4];
#pragma unroll
    for (int mi = 0; mi < 8; ++mi)
      af[mi] = *(const short8*)(bufA + (wr * 128 + mi * 16 + idx) * 32 + kgx);
#pragma unroll
    for (int ni = 0; ni < 4; ++ni)
      bfv[ni] = *(const short8*)(bufB + (wc * 64 + ni * 16 + idx) * 32 + kgx);
    __builtin_amdgcn_s_setprio(1);
#pragma unroll
    for (int mi = 0; mi < 8; ++mi)
#pragma unroll
      for (int ni = 0; ni < 4; ++ni)
        acc[mi][ni] = __builtin_amdgcn_mfma_f32_16x16x32_bf16(
            af[mi], bfv[ni], acc[mi][ni], 0, 0, 0);
    __builtin_amdgcn_s_setprio(0);
  }
#undef STAGE

  // epilogue: C/D layout col = lane&15, row = (lane>>4)*4 + j  [m89-verified]
  const int cr0 = (int)rowA + wr * 128;
  const int cc0 = (int)rowB + wc * 64;
#pragma unroll
  for (int mi = 0; mi < 8; ++mi) {
#pragma unroll
    for (int j = 0; j < 4; ++j) {
      const int r = cr0 + mi * 16 + kg * 4 + j;
      if (EPI == 0) {
        float ps = 0.0f;
#pragma unroll
        for (int ni = 0; ni < 4; ++ni) {
          const float v = acc[mi][ni][j];
          ps += v * v;
          Cb[(size_t)r * N + cc0 + ni * 16 + idx] = __float2bfloat16(v);
        }
        ps += __shfl_xor(ps, 1, 64);
        ps += __shfl_xor(ps, 2, 64);
        ps += __shfl_xor(ps, 4, 64);
        ps += __shfl_xor(ps, 8, 64);
        if (idx == 0) atomicAdd(ss + r, ps);
      } else {
        const float sc = 1.0f / fmaxf(sqrtf(ss[r]), 1e-12f);
#pragma unroll
        for (int ni = 0; ni < 4; ++ni) {
          const size_t off = (size_t)r * N + cc0 + ni * 16 + idx;
          if (EPI == 1) {
            const float v = acc[mi][ni][j] * sc;
            const float ge =
                0.5f * v * (1.0f + erff(v * 0.70710678118654752f));
            Cb[off] = __float2bfloat16(ge);
          } else {
            Cf[off] = acc[mi][ni][j] + sc * __bfloat162float(C1[off]);
          }
        }
      }
    }
  }
}

extern "C" void kernel_launch(void* const* d_in, const int* in_sizes, int n_in,
                              void* d_out, int out_size, void* d_ws,
                              size_t ws_size, hipStream_t stream) {
  const float* x = (const float*)d_in[0];
  const float* cw = (const float*)d_in[1];
  const float* cb = (const float*)d_in[2];
  const float* qw = (const float*)d_in[3];
  const float* w1 = (const float*)d_in[4];
  const float* w2 = (const float*)d_in[5];
  float* out = (float*)d_out;

  // ws layout (high-water 135.54 MB, under proven-safe 135.79 MB):
  //   [0, 64Mi)        x_conv bf16, reused as g (gelu out) after GEMM1
  //   [64Mi, 128Mi)    C1 bf16 (pre-normalize q-GEMM output; lives to GEMM3)
  //   [128Mi, +512K)   weight slot A (bf16)
  //   [+512K, +1M)     weight slot B (bf16)
  //   [+1M, +1M+8K)    cwt f32 [4][512]
  //   [+1M+8K, +1.25M) ss f32 [ML] row sum-of-squares
  char* ws = (char*)d_ws;
  __hip_bfloat16* xconv = (__hip_bfloat16*)ws;
  __hip_bfloat16* C1 = (__hip_bfloat16*)(ws + (size_t)67108864);
  __hip_bfloat16* wA = (__hip_bfloat16*)(ws + (size_t)134217728);
  __hip_bfloat16* wB = wA + DIM * DIM;
  float* cwt = (float*)(ws + (size_t)134217728 + 1048576);
  float* ss = (float*)(ws + (size_t)134217728 + 1048576 + 8192);
  __hip_bfloat16* g = xconv;  // alias: x_conv dead after GEMM1

  const int gemm_grid = (ML / 256) * (DIM / 256);  // 512 (%8==0 for T1)

  zero_ss<<<ML / 256, 256, 0, stream>>>(ss);
  prep_w<<<DIM * DIM / 256, 256, 0, stream>>>(qw, wA, 0, cw, cwt);
  prep_w<<<DIM * DIM / 256, 256, 0, stream>>>(w1, wB, 1, nullptr, nullptr);
  conv_cast_kernel<<<ML * (DIM / 4) / 256, 256, 0, stream>>>(x, cwt, cb, xconv);
  // GEMM1: C1 = x_conv @ q_w^T (bf16) + row sumsq -> ss
  gemm_bt<0><<<gemm_grid, 512, 0, stream>>>(xconv, wA, nullptr, C1, nullptr,
                                            ss, ML, DIM, DIM);
  prep_w<<<DIM * DIM / 256, 256, 0, stream>>>(w2, wA, 1, nullptr, nullptr);
  // GEMM2: g = gelu(sc * (C1 @ w1)) -> bf16 (into x_conv's region)
  gemm_bt<1><<<gemm_grid, 512, 0, stream>>>(C1, wB, nullptr, g, nullptr, ss,
                                            ML, DIM, DIM);
  // GEMM3: out = sc*C1 + g @ w2 -> f32
  gemm_bt<2><<<gemm_grid, 512, 0, stream>>>(g, wA, out, nullptr, C1, ss, ML,
                                            DIM, DIM);
}

// Round 7
// 274.900 us; speedup vs baseline: 1.3604x; 1.3604x over previous
//
#include <hip/hip_runtime.h>
#include <hip/hip_bf16.h>

#define DIM 512
#define BB 8
#define LL 8192
#define ML (BB * LL)  // 65536 rows

typedef __attribute__((ext_vector_type(4))) float f32x4;
typedef __attribute__((ext_vector_type(8))) short short8;

__device__ __forceinline__ void gl_lds16(const __hip_bfloat16* g, __hip_bfloat16* l) {
  __builtin_amdgcn_global_load_lds(
      (const __attribute__((address_space(1))) void*)g,
      (__attribute__((address_space(3))) void*)l, 16, 0, 0);
}

// inline-asm LDS read: compiler does not model this as an LDS-space read, so
// it cannot insert a conservative vmcnt(0) drain against global_load_lds
// writes. WE own the ordering: s_barrier + counted vmcnt before, lgkmcnt(0)
// + sched_barrier(0) after (rule #18).
__device__ __forceinline__ short8 ds_read128(const __hip_bfloat16* p) {
  short8 r;
  asm volatile("ds_read_b128 %0, %1"
               : "=v"(r)
               : "v"((const __attribute__((address_space(3))) void*)p));
  return r;
}

__device__ __forceinline__ unsigned short bf16_bits(float f) {
  __hip_bfloat16 h = __float2bfloat16(f);
  return *reinterpret_cast<unsigned short*>(&h);
}

// ---------------- zero the row-sumsq accumulator (deterministic, no memset) -
__global__ void zero_ss(float* __restrict__ ss) {
  ss[blockIdx.x * 256 + threadIdx.x] = 0.0f;
}

// ---------------- depthwise causal conv (K=4, left pad 3) + cast to bf16 ----
__global__ void conv_cast_kernel(const float* __restrict__ x,
                                 const float* __restrict__ cwt,
                                 const float* __restrict__ cb,
                                 __hip_bfloat16* __restrict__ xc) {
  const int tid = blockIdx.x * 256 + threadIdx.x;
  const int d = (tid & 127) << 2;  // 0..508 step 4
  const int bl = tid >> 7;
  const int l = bl & (LL - 1);
  float4 acc = *(const float4*)(cb + d);
  float4 w[4];
#pragma unroll
  for (int k = 0; k < 4; ++k) w[k] = *(const float4*)(cwt + k * DIM + d);
#pragma unroll
  for (int k = 0; k < 4; ++k) {
    if (l - 3 + k >= 0) {
      const float4 xv = *(const float4*)(x + (size_t)(bl - 3 + k) * DIM + d);
      acc.x += xv.x * w[k].x;
      acc.y += xv.y * w[k].y;
      acc.z += xv.z * w[k].z;
      acc.w += xv.w * w[k].w;
    }
  }
  ushort4 o;
  o.x = bf16_bits(acc.x);
  o.y = bf16_bits(acc.y);
  o.z = bf16_bits(acc.z);
  o.w = bf16_bits(acc.w);
  *(ushort4*)((unsigned short*)xc + (size_t)bl * DIM + d) = o;
}

// ---------------- weight prep: cast (or transpose-cast) one 512x512 weight --
__global__ void prep_w(const float* __restrict__ src,
                       __hip_bfloat16* __restrict__ dst, int transpose,
                       const float* __restrict__ cw, float* __restrict__ cwt) {
  const int i = blockIdx.x * 256 + threadIdx.x;  // 0..262143
  if (transpose)
    dst[(size_t)(i & 511) * DIM + (i >> 9)] = __float2bfloat16(src[i]);
  else
    dst[i] = __float2bfloat16(src[i]);
  if (cwt != nullptr && i < DIM * 4) cwt[(i & 3) * DIM + (i >> 2)] = cw[i];
}

// ---------------- GEMM: C[M,N] = A[M,K](bf16) @ Bt[N,K](bf16)^T, f32 acc ----
// 128x128 tile, BK=32, 4 waves (2x2). 3-buffer ring, depth-2 prefetch,
// raw s_barrier + counted vmcnt, inline-asm ds_read (escapes compiler's
// conservative vmcnt(0) drain). T2 chunk-swizzle, T1 XCD swizzle, T5 setprio.
// EPI 0: write C1 bf16 + per-row sum-of-squares atomics into ss
// EPI 1: v *= 1/max(sqrt(ss[r]),eps); exact GELU -> bf16
// EPI 2: out f32 = v + (1/max(sqrt(ss[r]),eps)) * C1_bf16[off]  (residual q)
template <int EPI>
__global__ __launch_bounds__(256) void gemm_bt(
    const __hip_bfloat16* __restrict__ A, const __hip_bfloat16* __restrict__ Bt,
    float* __restrict__ Cf, __hip_bfloat16* __restrict__ Cb,
    const __hip_bfloat16* __restrict__ C1, float* __restrict__ ss, int M,
    int N, int K) {
  __shared__ __hip_bfloat16 sA[3][128 * 32];
  __shared__ __hip_bfloat16 sB[3][128 * 32];
  // T1: XCD-chunked swizzle (gridDim %8 == 0 here: 2048)
  const int nbn = N >> 7;
  const int bid = blockIdx.x;
  const int swz = (bid & 7) * (gridDim.x >> 3) + (bid >> 3);
  const int bm = swz / nbn;
  const int bn = swz - bm * nbn;
  const int tid = threadIdx.x;
  const int wv = tid >> 6, ln = tid & 63;
  const int wr = wv >> 1, wc = wv & 1;
  const int idx = ln & 15, kg = ln >> 4;
  const size_t rowA = (size_t)bm * 128, rowB = (size_t)bn * 128;

  f32x4 acc[4][4] = {};

  // staging: slot s = (wv*2+i)*64 + ln -> LDS bytes [s*16, s*16+16)
  // row = s>>2, chunk kc = s&3. T2: LDS slot (row,kc) holds global chunk
  // kc ^ ((row>>1)&3); for this slot map that is (ln&3)^((ln>>3)&3).
  const int r0 = (wv * 2 + 0) * 16 + (ln >> 2);
  const int r1 = (wv * 2 + 1) * 16 + (ln >> 2);
  const int kcl = (((ln & 3) ^ ((ln >> 3) & 3)) << 3);  // elements
  // read side: global chunk kg of row lives in LDS chunk kg ^ ((idx>>1)&3)
  const int kgx = ((kg ^ ((idx >> 1) & 3)) << 3);  // elements

  const __hip_bfloat16* gA0 = A + (rowA + r0) * K + kcl;
  const __hip_bfloat16* gA1 = A + (rowA + r1) * K + kcl;
  const __hip_bfloat16* gB0 = Bt + (rowB + r0) * K + kcl;
  const __hip_bfloat16* gB1 = Bt + (rowB + r1) * K + kcl;
  const int lo0 = (wv * 2 + 0) * 512, lo1 = (wv * 2 + 1) * 512;

  const int nt = K >> 5;  // 16 K-steps

#define STAGE(t, b)                     \
  do {                                  \
    const int k0_ = (t) << 5;           \
    gl_lds16(gA0 + k0_, &sA[(b)][lo0]); \
    gl_lds16(gA1 + k0_, &sA[(b)][lo1]); \
    gl_lds16(gB0 + k0_, &sB[(b)][lo0]); \
    gl_lds16(gB1 + k0_, &sB[(b)][lo1]); \
  } while (0)

  // prologue: fill ring slots 0,1 (8 vm instructions outstanding)
  STAGE(0, 0);
  STAGE(1, 1);

  int rb = 0;  // read buffer; write slot = (rb+2)%3
  for (int t = 0; t < nt; ++t) {
    // gate: my stage(t) landed; stage(t+1) may stay in flight
    if (t + 1 < nt)
      asm volatile("s_waitcnt vmcnt(4)" ::: "memory");
    else
      asm volatile("s_waitcnt vmcnt(0)" ::: "memory");
    // all waves passed their gate (tile t in LDS everywhere) AND executed
    // iter t-1's lgkmcnt(0) (all reads of buf[(t+2)%3] retired -> WAR-safe)
    asm volatile("s_barrier" ::: "memory");
    if (t + 2 < nt) {
      const int wbuf = rb < 1 ? rb + 2 : rb - 1;  // (rb+2)%3
      STAGE(t + 2, wbuf);
    }
    short8 af[4], bfv[4];
#pragma unroll
    for (int mi = 0; mi < 4; ++mi)
      af[mi] = ds_read128(&sA[rb][(wr * 64 + mi * 16 + idx) * 32 + kgx]);
#pragma unroll
    for (int ni = 0; ni < 4; ++ni)
      bfv[ni] = ds_read128(&sB[rb][(wc * 64 + ni * 16 + idx) * 32 + kgx]);
    asm volatile("s_waitcnt lgkmcnt(0)" ::: "memory");
    __builtin_amdgcn_sched_barrier(0);  // rule #18: keep MFMA below the wait
    __builtin_amdgcn_s_setprio(1);
#pragma unroll
    for (int mi = 0; mi < 4; ++mi)
#pragma unroll
      for (int ni = 0; ni < 4; ++ni)
        acc[mi][ni] = __builtin_amdgcn_mfma_f32_16x16x32_bf16(
            af[mi], bfv[ni], acc[mi][ni], 0, 0, 0);
    __builtin_amdgcn_s_setprio(0);
    rb = rb == 2 ? 0 : rb + 1;
  }
#undef STAGE

  // epilogue: C/D layout col = lane&15, row = (lane>>4)*4 + j  [m89-verified]
  const int cr0 = (int)rowA + wr * 64;
  const int cc0 = (int)rowB + wc * 64;
#pragma unroll
  for (int mi = 0; mi < 4; ++mi) {
#pragma unroll
    for (int j = 0; j < 4; ++j) {
      const int r = cr0 + mi * 16 + kg * 4 + j;
      if (EPI == 0) {
        float ps = 0.0f;
#pragma unroll
        for (int ni = 0; ni < 4; ++ni) {
          const float v = acc[mi][ni][j];
          ps += v * v;
          Cb[(size_t)r * N + cc0 + ni * 16 + idx] = __float2bfloat16(v);
        }
        ps += __shfl_xor(ps, 1, 64);
        ps += __shfl_xor(ps, 2, 64);
        ps += __shfl_xor(ps, 4, 64);
        ps += __shfl_xor(ps, 8, 64);
        if (idx == 0) atomicAdd(ss + r, ps);
      } else {
        const float sc = 1.0f / fmaxf(sqrtf(ss[r]), 1e-12f);
#pragma unroll
        for (int ni = 0; ni < 4; ++ni) {
          const size_t off = (size_t)r * N + cc0 + ni * 16 + idx;
          if (EPI == 1) {
            const float v = acc[mi][ni][j] * sc;
            const float ge =
                0.5f * v * (1.0f + erff(v * 0.70710678118654752f));
            Cb[off] = __float2bfloat16(ge);
          } else {
            Cf[off] = acc[mi][ni][j] + sc * __bfloat162float(C1[off]);
          }
        }
      }
    }
  }
}

extern "C" void kernel_launch(void* const* d_in, const int* in_sizes, int n_in,
                              void* d_out, int out_size, void* d_ws,
                              size_t ws_size, hipStream_t stream) {
  const float* x = (const float*)d_in[0];
  const float* cw = (const float*)d_in[1];
  const float* cb = (const float*)d_in[2];
  const float* qw = (const float*)d_in[3];
  const float* w1 = (const float*)d_in[4];
  const float* w2 = (const float*)d_in[5];
  float* out = (float*)d_out;

  // ws layout (high-water 135.54 MB, under proven-safe 135.79 MB):
  //   [0, 64Mi)        x_conv bf16, reused as g (gelu out) after GEMM1
  //   [64Mi, 128Mi)    C1 bf16 (pre-normalize q-GEMM output; lives to GEMM3)
  //   [128Mi, +512K)   weight slot A (bf16)
  //   [+512K, +1M)     weight slot B (bf16)
  //   [+1M, +1M+8K)    cwt f32 [4][512]
  //   [+1M+8K, +1.25M) ss f32 [ML] row sum-of-squares
  char* ws = (char*)d_ws;
  __hip_bfloat16* xconv = (__hip_bfloat16*)ws;
  __hip_bfloat16* C1 = (__hip_bfloat16*)(ws + (size_t)67108864);
  __hip_bfloat16* wA = (__hip_bfloat16*)(ws + (size_t)134217728);
  __hip_bfloat16* wB = wA + DIM * DIM;
  float* cwt = (float*)(ws + (size_t)134217728 + 1048576);
  float* ss = (float*)(ws + (size_t)134217728 + 1048576 + 8192);
  __hip_bfloat16* g = xconv;  // alias: x_conv dead after GEMM1

  const int gemm_grid = (ML / 128) * (DIM / 128);  // 2048 (%8==0 for T1)

  zero_ss<<<ML / 256, 256, 0, stream>>>(ss);
  prep_w<<<DIM * DIM / 256, 256, 0, stream>>>(qw, wA, 0, cw, cwt);
  prep_w<<<DIM * DIM / 256, 256, 0, stream>>>(w1, wB, 1, nullptr, nullptr);
  conv_cast_kernel<<<ML * (DIM / 4) / 256, 256, 0, stream>>>(x, cwt, cb, xconv);
  // GEMM1: C1 = x_conv @ q_w^T (bf16) + row sumsq -> ss
  gemm_bt<0><<<gemm_grid, 256, 0, stream>>>(xconv, wA, nullptr, C1, nullptr,
                                            ss, ML, DIM, DIM);
  prep_w<<<DIM * DIM / 256, 256, 0, stream>>>(w2, wA, 1, nullptr, nullptr);
  // GEMM2: g = gelu(sc * (C1 @ w1)) -> bf16 (into x_conv's region)
  gemm_bt<1><<<gemm_grid, 256, 0, stream>>>(C1, wB, nullptr, g, nullptr, ss,
                                            ML, DIM, DIM);
  // GEMM3: out = sc*C1 + g @ w2 -> f32
  gemm_bt<2><<<gemm_grid, 256, 0, stream>>>(g, wA, out, nullptr, C1, ss, ML,
                                            DIM, DIM);
}